// Round 7
// baseline (350.762 us; speedup 1.0000x reference)
//
#include <hip/hip_runtime.h>

// B=16, N=2048, C=128, S=25, D_AGG=128, D_OUT=128
// in: A[16,2048,2048] f32, X[16,2048,128] f32, Wa[128,128] f32, ba[128] f32,
//     Wc[256,128] f32, bc[128] f32, n_samples i32
// out: [16,2048,128] f32
//
// Persistent mega-kernel (512 blocks, 2/CU, 48 KB LDS, 3 spin barriers):
//   prep : Wat/Wct bf16^T + zero barrier counters (replay-safe)
//   mega : P1a K1 GEMM (64-row tile/block, batch-affine -> H in local L2)
//          bar0 | P1b scan+gather 16 groups/block (R4 wave code, A prefetch)
//          bar1 | P2 K3 GEMM (ktiles=2, acc in regs, sumsq partials)
//          bar2 | P3 normalize in regs (div_no_nan), single store
//
// ws: H 8MB @0, agg 8MB @8M, Wat 32K @16M, Wct 64K @+32K, partials 2K @+128K,
//     ctr[4] @+132K

typedef __attribute__((ext_vector_type(8))) short short8;   // bf16x8 raw bits
typedef __attribute__((ext_vector_type(4))) float f32x4;
typedef __attribute__((ext_vector_type(4))) float fvec4;
typedef unsigned int uint;
typedef unsigned short ushort;

__device__ __forceinline__ ushort f2bf(float x) {           // RNE f32->bf16
    uint u = __builtin_bit_cast(uint, x);
    u += 0x7FFFu + ((u >> 16) & 1u);
    return (ushort)(u >> 16);
}
__device__ __forceinline__ float bflo(uint h) { uint v = h << 16;         return __builtin_bit_cast(float, v); }
__device__ __forceinline__ float bfhi(uint h) { uint v = h & 0xFFFF0000u; return __builtin_bit_cast(float, v); }

// ---------------------------------------------------------------------------
// prep: Wat[d*128+k]=bf16(Wa[k][d]); Wct[d*256+k]=bf16(Wc[k][d]); zero ctrs.
// ---------------------------------------------------------------------------
__global__ __launch_bounds__(256) void prep_k(
    const float* __restrict__ Wa, const float* __restrict__ Wc,
    ushort* __restrict__ Wat, ushort* __restrict__ Wct, uint* __restrict__ ctr)
{
    int i = blockIdx.x * 256 + threadIdx.x;     // < 49152
    if (i < 16384) {
        int d = i >> 7, k = i & 127;
        Wat[i] = f2bf(Wa[k * 128 + d]);
    } else {
        int j = i - 16384;
        int d = j >> 8, k = j & 255;
        Wct[j] = f2bf(Wc[k * 128 + d]);
    }
    if (blockIdx.x == 0 && threadIdx.x < 4) ctr[threadIdx.x] = 0u;  // replay-safe
}

// ---------------------------------------------------------------------------
// Device-scope arrive-and-spin barrier (R6-proven pattern). 512 blocks are
// guaranteed co-resident (2 blocks/CU x 256 CUs; LDS 48KB<=80, VGPR<=256).
// ---------------------------------------------------------------------------
__device__ __forceinline__ void gbar(uint* c, int tid) {
    __syncthreads();
    if (tid == 0) {
        __threadfence();                         // release our writes
        __hip_atomic_fetch_add(c, 1u, __ATOMIC_ACQ_REL,
                               __HIP_MEMORY_SCOPE_AGENT);
        while (__hip_atomic_load(c, __ATOMIC_ACQUIRE,
                                 __HIP_MEMORY_SCOPE_AGENT) < 512u)
            __builtin_amdgcn_s_sleep(4);
    }
    __syncthreads();
    __threadfence();                             // acquire others' writes
}

// ---------------------------------------------------------------------------
// 64-row MFMA GEMM tile: 4 waves, wave = 64 rows x 32 cols = 4x2 frags of
// 16x16x32. Chunk0 converted from fp32, chunk1 bf16. B pre-transposed
// [col][KT]. LDS XOR swizzle on 16B granules (write AND read).
// ---------------------------------------------------------------------------
__device__ __forceinline__ void gemm64(
    const float*  __restrict__ Xf, const ushort* __restrict__ A1,
    const ushort* __restrict__ Bt, int KT, int ktiles, int tile64,
    int tid, ushort* Asm, ushort* Bsm, f32x4 acc[4][2])
{
    const int l = tid & 63, w = tid >> 6;
    const int wn = w * 32;
    const size_t row0 = (size_t)tile64 * 64;

    for (int t = 0; t < ktiles; ++t) {
        __syncthreads();
        if (t == 0) {
#pragma unroll
            for (int j = 0; j < 4; ++j) {        // Asm: 64x16 granules
                int gid = (j << 8) + tid;
                int r = gid >> 4, g = gid & 15;
                const float* s = Xf + (row0 + r) * 128 + g * 8;
                short8 pk;
#pragma unroll
                for (int e = 0; e < 8; ++e) pk[e] = (short)f2bf(s[e]);
                *(short8*)&Asm[r * 128 + ((g ^ (r & 7)) << 3)] = pk;
            }
        } else {
#pragma unroll
            for (int j = 0; j < 4; ++j) {
                int gid = (j << 8) + tid;
                int r = gid >> 4, g = gid & 15;
                short8 v = *(const short8*)(A1 + (row0 + r) * 128 + g * 8);
                *(short8*)&Asm[r * 128 + ((g ^ (r & 7)) << 3)] = v;
            }
        }
#pragma unroll
        for (int j = 0; j < 8; ++j) {            // Bsm: 128x16 granules
            int gid = (j << 8) + tid;
            int c = gid >> 4, g = gid & 15;
            short8 v = *(const short8*)(Bt + (size_t)c * KT + (t << 7) + g * 8);
            *(short8*)&Bsm[c * 128 + ((g ^ (c & 7)) << 3)] = v;
        }
        __syncthreads();
#pragma unroll
        for (int ks = 0; ks < 4; ++ks) {
            int gg = (ks << 2) + (l >> 4);
            short8 af[4], bfr[2];
#pragma unroll
            for (int m = 0; m < 4; ++m) {
                int r = m * 16 + (l & 15);
                af[m] = *(const short8*)&Asm[r * 128 + ((gg ^ (r & 7)) << 3)];
            }
#pragma unroll
            for (int n = 0; n < 2; ++n) {
                int c = wn + n * 16 + (l & 15);
                bfr[n] = *(const short8*)&Bsm[c * 128 + ((gg ^ (c & 7)) << 3)];
            }
#pragma unroll
            for (int m = 0; m < 4; ++m)
#pragma unroll
                for (int n = 0; n < 2; ++n)
                    acc[m][n] = __builtin_amdgcn_mfma_f32_16x16x32_bf16(
                        af[m], bfr[n], acc[m][n], 0, 0, 0);
        }
    }
}

// ---------------------------------------------------------------------------
// mega: block bid -> xcd = bid&7, rank rk = bid>>3 (0..63); batch =
// rk<32 ? xcd : xcd+8 (batch-affine: one XCD touches 2 batches); tile64 =
// batch*32 + (rk&31) covers that batch's rows for K1/K3/out; the block's 16
// scan groups are the same batch's nodes (H gathers hit local L2).
// ---------------------------------------------------------------------------
__global__ __launch_bounds__(256, 2) void mega_k(
    const float* __restrict__ A, const float* __restrict__ X,
    const ushort* __restrict__ Wat, const ushort* __restrict__ Wct,
    const float* __restrict__ ba, const float* __restrict__ bc,
    ushort* __restrict__ H, uint* __restrict__ aggu,
    float* __restrict__ out, float* __restrict__ partials,
    uint* __restrict__ ctr, const int* __restrict__ nsp)
{
    __shared__ ushort Asm[64 * 128];
    __shared__ ushort Bsm[128 * 128];
    __shared__ float wred[4];
    __shared__ float ssc;

    const int tid = threadIdx.x, l = tid & 63, w = tid >> 6;
    const int bid = blockIdx.x;
    const int xcd = bid & 7, rk = bid >> 3;
    const int b_blk = (rk < 32) ? xcd : xcd + 8;
    const int rk2 = rk & 31;
    const int tile64 = b_blk * 32 + rk2;
    const int wn = w * 32;
    const size_t row0 = (size_t)tile64 * 64;

    // ---- P1a: K1 tile  H = relu(X @ Wa + ba) ----
    {
        f32x4 acc[4][2] = {};
        gemm64(X, nullptr, Wat, 128, 1, tile64, tid, Asm, Bsm, acc);
        float bcol[2];
#pragma unroll
        for (int n = 0; n < 2; ++n) bcol[n] = ba[wn + n * 16 + (l & 15)];
#pragma unroll
        for (int m = 0; m < 4; ++m) {
            int rbase = m * 16 + ((l >> 4) << 2);    // C/D: row = 4*(l>>4)+reg
#pragma unroll
            for (int n = 0; n < 2; ++n) {
                int col = wn + n * 16 + (l & 15);    // C/D: col = l&15
#pragma unroll
                for (int r = 0; r < 4; ++r)
                    H[(row0 + rbase + r) * 128 + col] =
                        f2bf(fmaxf(acc[m][n][r] + bcol[n], 0.f));
            }
        }
    }
    gbar(&ctr[0], tid);                              // H ready (all batches)

    // ---- P1b: scan + gather, 16 groups (R4 wave code + A prefetch) ----
    {
        int S = nsp[0]; if (S > 32) S = 32;
        int* idxs = (int*)Asm;                       // [4][32], aliases Asm
        const uint* HB = (const uint*)H + ((size_t)b_blk << 17);
        const float i0 = fmaxf(ba[2 * l], 0.f), i1 = fmaxf(ba[2 * l + 1], 0.f);
        const unsigned long long lt = (1ull << l) - 1ull;
        const int nodeb = (b_blk << 11) + (rk2 << 6);    // 16 groups x 4 nodes

        fvec4 v[8];
        {
            const fvec4* rp = (const fvec4*)(A + (size_t)(nodeb + w) * 2048);
#pragma unroll
            for (int c = 0; c < 8; ++c)
                v[c] = __builtin_nontemporal_load(rp + c * 64 + l);
        }
        for (int i = 0; i < 16; ++i) {
            const int node = nodeb + i * 4 + w;
            int base = 0;
#pragma unroll
            for (int c = 0; c < 8; ++c) {
                if (base < S) {                      // wave-uniform skip
                    unsigned long long m0 = __ballot(v[c][0] != 0.f);
                    unsigned long long m1 = __ballot(v[c][1] != 0.f);
                    unsigned long long m2 = __ballot(v[c][2] != 0.f);
                    unsigned long long m3 = __ballot(v[c][3] != 0.f);
                    int below = __popcll(m0 & lt) + __popcll(m1 & lt)
                              + __popcll(m2 & lt) + __popcll(m3 & lt);
                    int o0 = (int)((m0 >> l) & 1), o1 = (int)((m1 >> l) & 1);
                    int o2 = (int)((m2 >> l) & 1), o3 = (int)((m3 >> l) & 1);
                    int r0 = base + below;
                    int r1 = r0 + o0, r2 = r1 + o1, r3 = r2 + o2;
                    int e = (c << 8) + (l << 2);
                    if (o0 && r0 < S) idxs[w * 32 + r0] = e;
                    if (o1 && r1 < S) idxs[w * 32 + r1] = e + 1;
                    if (o2 && r2 < S) idxs[w * 32 + r2] = e + 2;
                    if (o3 && r3 < S) idxs[w * 32 + r3] = e + 3;
                    base += __popcll(m0) + __popcll(m1)
                          + __popcll(m2) + __popcll(m3);
                }
            }
            const int found = base < S ? base : S;
            const bool have = found > 0;             // wave-uniform

            uint h[32];
            if (have) {
                int fill = idxs[w * 32];             // broadcast read
                if (l < 32)                          // pad list to 32
                    idxs[w * 32 + l] = (l < found) ? idxs[w * 32 + l] : fill;
#pragma unroll
                for (int q = 0; q < 32; ++q)         // all 32 in flight (L2)
                    h[q] = HB[(size_t)idxs[w * 32 + q] * 64 + l];
            }
            if (i < 15) {                            // prefetch next A row
                const fvec4* rp =
                    (const fvec4*)(A + (size_t)(nodeb + (i + 1) * 4 + w) * 2048);
#pragma unroll
                for (int c = 0; c < 8; ++c)
                    v[c] = __builtin_nontemporal_load(rp + c * 64 + l);
            }
            float r0f = i0, r1f = i1;
            if (have) {
                float a0[8], a1[8];
#pragma unroll
                for (int q = 0; q < 8; ++q) { a0[q] = i0; a1[q] = i1; }
#pragma unroll
                for (int q = 0; q < 32; ++q) {
                    a0[q & 7] = fmaxf(a0[q & 7], bflo(h[q]));
                    a1[q & 7] = fmaxf(a1[q & 7], bfhi(h[q]));
                }
#pragma unroll
                for (int q = 0; q < 4; ++q) {
                    a0[q] = fmaxf(a0[q], a0[q + 4]);
                    a1[q] = fmaxf(a1[q], a1[q + 4]);
                }
                r0f = fmaxf(fmaxf(a0[0], a0[1]), fmaxf(a0[2], a0[3]));
                r1f = fmaxf(fmaxf(a1[0], a1[1]), fmaxf(a1[2], a1[3]));
            }
            aggu[(size_t)node * 64 + l] =
                (uint)f2bf(r0f) | ((uint)f2bf(r1f) << 16);
        }
    }
    gbar(&ctr[1], tid);                              // agg ready

    // ---- P2: K3 tile  out = relu([X|agg] @ Wc + bc), partial sumsq ----
    f32x4 acc[4][2] = {};
    gemm64(X, (const ushort*)aggu, Wct, 256, 2, tile64, tid, Asm, Bsm, acc);
    {
        float bcol[2];
#pragma unroll
        for (int n = 0; n < 2; ++n) bcol[n] = bc[wn + n * 16 + (l & 15)];
        float lsum = 0.f;
#pragma unroll
        for (int m = 0; m < 4; ++m)
#pragma unroll
            for (int n = 0; n < 2; ++n)
#pragma unroll
                for (int r = 0; r < 4; ++r) {
                    float vv = fmaxf(acc[m][n][r] + bcol[n], 0.f);
                    acc[m][n][r] = vv;               // keep relu'd value
                    lsum += vv * vv;
                }
#pragma unroll
        for (int off = 32; off > 0; off >>= 1) lsum += __shfl_down(lsum, off);
        if (l == 0) wred[w] = lsum;
        __syncthreads();
        if (tid == 0)
            partials[tile64] = wred[0] + wred[1] + wred[2] + wred[3];
    }
    gbar(&ctr[2], tid);                              // partials ready

    // ---- P3: per-batch frobenius normalize in registers (div_no_nan) ----
    if (tid == 0) {
        float s = 0.f;
#pragma unroll
        for (int i = 0; i < 32; ++i) s += partials[b_blk * 32 + i];
        float norm = sqrtf(s);
        ssc = (norm > 0.f) ? (1.f / norm) : 0.f;
    }
    __syncthreads();
    const float sc = ssc;
#pragma unroll
    for (int m = 0; m < 4; ++m) {
        int rbase = m * 16 + ((l >> 4) << 2);
#pragma unroll
        for (int n = 0; n < 2; ++n) {
            int col = wn + n * 16 + (l & 15);
#pragma unroll
            for (int r = 0; r < 4; ++r)
                out[(row0 + rbase + r) * 128 + col] = acc[m][n][r] * sc;
        }
    }
}

extern "C" void kernel_launch(void* const* d_in, const int* in_sizes, int n_in,
                              void* d_out, int out_size, void* d_ws, size_t ws_size,
                              hipStream_t stream) {
    const float* A  = (const float*)d_in[0];
    const float* X  = (const float*)d_in[1];
    const float* Wa = (const float*)d_in[2];
    const float* ba = (const float*)d_in[3];
    const float* Wc = (const float*)d_in[4];
    const float* bc = (const float*)d_in[5];
    const int*  nsp = (const int*)d_in[6];

    float* out = (float*)d_out;
    char* ws = (char*)d_ws;
    ushort* H        = (ushort*)ws;                              // 8 MB
    uint*   agg      = (uint*)  (ws + (8u << 20));               // 8 MB
    ushort* Wat      = (ushort*)(ws + (16u << 20));              // 32 KB
    ushort* Wct      = (ushort*)(ws + (16u << 20) + 32768);      // 64 KB
    float*  partials = (float*) (ws + (16u << 20) + 131072);     // 2 KB
    uint*   ctr      = (uint*)  (ws + (16u << 20) + 133120);     // 16 B

    prep_k<<<192, 256, 0, stream>>>(Wa, Wc, Wat, Wct, ctr);
    mega_k<<<512, 256, 0, stream>>>(A, X, Wat, Wct, ba, bc,
                                    H, agg, out, partials, ctr, nsp);
}

// Round 9
// 96.330 us; speedup vs baseline: 3.6413x; 3.6413x over previous
//
#include <hip/hip_runtime.h>

// B=16, N=2048, C=128, S=25, D_AGG=128, D_OUT=128
// in: A[16,2048,2048] f32, X[16,2048,128] f32, Wa[128,128] f32, ba[128] f32,
//     Wc[256,128] f32, bc[128] f32, n_samples i32
// out: [16,2048,128] f32
//
// Pipeline (R8 structure, GLOBAL-index fix in scan):
//   K1     : H = relu(X @ Wa + ba) -> bf16 [32769][128] (MFMA; Wa transposed
//            +converted inline; block 0 writes sentinel row 32768 = relu(ba))
//   scan   : pure A-stream; ballot-rank scan -> first min(deg,S) ascending
//            GLOBAL indices (== lax.top_k of binary mask + batch offset) ->
//            padded 32-slot idx lists (pad = first idx, or sentinel 32768).
//            Blocks >= 8192: Wct prep + zero K3 barrier ctr (replay-safe).
//   gather : agg[node] = max over 32 idx'd H rows (branch-free, L2-resident;
//            batch-affine XCD mapping)
//   K3     : out = relu([X|agg] @ Wc + bc); grid barrier; in-register
//            frobenius normalize (div_no_nan); single store.
//
// ws: H 8.4MB @0, agg 8MB @9M, idxg 2MB @17M, Wct 64K @19M,
//     partials 1K @19M+64K, ctr @19M+66K

typedef __attribute__((ext_vector_type(8))) short short8;   // bf16x8 raw bits
typedef __attribute__((ext_vector_type(4))) float f32x4;
typedef __attribute__((ext_vector_type(4))) float fvec4;
typedef unsigned int uint;
typedef unsigned short ushort;

__device__ __forceinline__ ushort f2bf(float x) {           // RNE f32->bf16
    uint u = __builtin_bit_cast(uint, x);
    u += 0x7FFFu + ((u >> 16) & 1u);
    return (ushort)(u >> 16);
}
__device__ __forceinline__ float bflo(uint h) { uint v = h << 16;         return __builtin_bit_cast(float, v); }
__device__ __forceinline__ float bfhi(uint h) { uint v = h & 0xFFFF0000u; return __builtin_bit_cast(float, v); }

// ---------------------------------------------------------------------------
// K1: H = relu(X @ Wa + ba) -> bf16. 128x128 tile, 4 waves 2x2, wave = 64x64
// = 4x4 frags of 16x16x32. A staged from fp32 X (convert); B staged by
// inline transpose+convert of Wa (64 KB, L2-broadcast across blocks).
// LDS XOR swizzle on 16B granules (write AND read). Block 0 also writes the
// sentinel H row 32768 = relu(ba) (degree-0 / padding target).
// ---------------------------------------------------------------------------
__global__ __launch_bounds__(256) void gemm_k1_k(
    const float* __restrict__ X, const float* __restrict__ Wa,
    const float* __restrict__ ba, ushort* __restrict__ H)
{
    __shared__ ushort Asm[128 * 128];
    __shared__ ushort Bsm[128 * 128];
    const int tid = threadIdx.x, l = tid & 63, w = tid >> 6;
    const int wm = (w >> 1) * 64, wn = (w & 1) * 64;
    const size_t row0 = (size_t)blockIdx.x * 128;

    // stage A: X f32 -> bf16, swizzled
#pragma unroll
    for (int j = 0; j < 8; ++j) {
        int gid = (j << 8) + tid;              // 16B granule id
        int r = gid >> 4, g = gid & 15;
        const float* s = X + (row0 + r) * 128 + g * 8;
        short8 pk;
#pragma unroll
        for (int e = 0; e < 8; ++e) pk[e] = (short)f2bf(s[e]);
        *(short8*)&Asm[r * 128 + ((g ^ (r & 7)) << 3)] = pk;
    }
    // stage B: Wa[k][d] f32 -> Bsm[d][k] bf16 (inline transpose+convert)
    {
        int c = tid >> 1;                      // output col d
        int g0 = (tid & 1) * 8;                // granule half
#pragma unroll
        for (int g = g0; g < g0 + 8; ++g) {
            short8 pk;
#pragma unroll
            for (int e = 0; e < 8; ++e)
                pk[e] = (short)f2bf(Wa[(size_t)(g * 8 + e) * 128 + c]);
            *(short8*)&Bsm[c * 128 + ((g ^ (c & 7)) << 3)] = pk;
        }
    }
    __syncthreads();

    f32x4 acc[4][4] = {};
#pragma unroll
    for (int ks = 0; ks < 4; ++ks) {
        int gg = (ks << 2) + (l >> 4);
        short8 af[4], bfr[4];
#pragma unroll
        for (int m = 0; m < 4; ++m) {
            int r = wm + m * 16 + (l & 15);
            af[m] = *(const short8*)&Asm[r * 128 + ((gg ^ (r & 7)) << 3)];
        }
#pragma unroll
        for (int n = 0; n < 4; ++n) {
            int c = wn + n * 16 + (l & 15);
            bfr[n] = *(const short8*)&Bsm[c * 128 + ((gg ^ (c & 7)) << 3)];
        }
#pragma unroll
        for (int m = 0; m < 4; ++m)
#pragma unroll
            for (int n = 0; n < 4; ++n)
                acc[m][n] = __builtin_amdgcn_mfma_f32_16x16x32_bf16(
                    af[m], bfr[n], acc[m][n], 0, 0, 0);
    }

    float bcol[4];
#pragma unroll
    for (int n = 0; n < 4; ++n) bcol[n] = ba[wn + n * 16 + (l & 15)];
#pragma unroll
    for (int m = 0; m < 4; ++m) {
        int rbase = wm + m * 16 + ((l >> 4) << 2);   // C/D: row = 4*(l>>4)+reg
#pragma unroll
        for (int n = 0; n < 4; ++n) {
            int col = wn + n * 16 + (l & 15);        // C/D: col = l&15
#pragma unroll
            for (int r = 0; r < 4; ++r)
                H[(row0 + rbase + r) * 128 + col] =
                    f2bf(fmaxf(acc[m][n][r] + bcol[n], 0.f));
        }
    }
    if (blockIdx.x == 0 && tid < 64) {               // sentinel row
        float a = fmaxf(ba[2 * tid], 0.f), b = fmaxf(ba[2 * tid + 1], 0.f);
        ((uint*)(H + (size_t)32768 * 128))[tid] =
            (uint)f2bf(a) | ((uint)f2bf(b) << 16);
    }
}

// ---------------------------------------------------------------------------
// scan: one wave per node, pure A-stream (no gather tail -> block slots keep
// issuing HBM loads; tiny LDS/VGPR for max occupancy). Rank-based ballot
// scan gives each nonzero its ascending-index rank; rank<S scatters to LDS;
// padded 32-slot list of GLOBAL indices (node row in [32768] H; fits ushort,
// sentinel 32768) written to idxg (pad = idxs[0], sentinel when deg==0).
// Blocks >= 8192: Wct[d*256+k]=bf16(Wc[k][d]) + zero barrier ctr.
// ---------------------------------------------------------------------------
__global__ __launch_bounds__(256) void scan_k(
    const float* __restrict__ A,        // [32768][2048]
    ushort* __restrict__ idxg,          // [32768][32]
    const int* __restrict__ nsp,
    const float* __restrict__ Wc,
    ushort* __restrict__ Wct,
    uint* __restrict__ ctr)
{
    if (blockIdx.x >= 8192) {           // folded Wct prep: 128 blocks
        int j = (blockIdx.x - 8192) * 256 + threadIdx.x;   // < 32768
        int d = j >> 8, k = j & 255;
        Wct[j] = f2bf(Wc[k * 128 + d]);
        if (blockIdx.x == 8192 && threadIdx.x == 0) *ctr = 0u;  // replay-safe
        return;
    }

    __shared__ int idxs[4][32];
    const int l = threadIdx.x & 63;
    const int w = threadIdx.x >> 6;
    const int node = blockIdx.x * 4 + w;
    const int gbase = node & ~2047;     // batch<<11 : GLOBAL H row base
    int S = nsp[0]; if (S > 32) S = 32;

    const fvec4* rowp = (const fvec4*)(A + (size_t)node * 2048);
    fvec4 v[8];
#pragma unroll
    for (int c = 0; c < 8; ++c)
        v[c] = __builtin_nontemporal_load(rowp + c * 64 + l);

    const unsigned long long lt = (1ull << l) - 1ull;
    int base = 0;
#pragma unroll
    for (int c = 0; c < 8; ++c) {
        if (base < S) {                              // wave-uniform skip
            unsigned long long m0 = __ballot(v[c][0] != 0.f);
            unsigned long long m1 = __ballot(v[c][1] != 0.f);
            unsigned long long m2 = __ballot(v[c][2] != 0.f);
            unsigned long long m3 = __ballot(v[c][3] != 0.f);
            int below = __popcll(m0 & lt) + __popcll(m1 & lt)
                      + __popcll(m2 & lt) + __popcll(m3 & lt);
            int o0 = (int)((m0 >> l) & 1), o1 = (int)((m1 >> l) & 1);
            int o2 = (int)((m2 >> l) & 1), o3 = (int)((m3 >> l) & 1);
            int r0 = base + below;
            int r1 = r0 + o0, r2 = r1 + o1, r3 = r2 + o2;
            int e = gbase + (c << 8) + (l << 2);     // GLOBAL index (fix)
            if (o0 && r0 < S) idxs[w][r0] = e;
            if (o1 && r1 < S) idxs[w][r1] = e + 1;
            if (o2 && r2 < S) idxs[w][r2] = e + 2;
            if (o3 && r3 < S) idxs[w][r3] = e + 3;
            base += __popcll(m0) + __popcll(m1) + __popcll(m2) + __popcll(m3);
        }
    }
    int found = base < S ? base : S;
    int fill = (found > 0) ? idxs[w][0] : 32768;     // sentinel if deg==0
    if (l < 32)
        idxg[(size_t)node * 32 + l] =
            (ushort)((l < found) ? idxs[w][l] : fill);
}

// ---------------------------------------------------------------------------
// gather: one wave per node; batch-affine XCD mapping (batch = {xcd, xcd+8})
// keeps each batch's 512 KB H slice in one XCD's L2. Branch-free 32-wide
// gather-max via padded GLOBAL index lists. acc init = relu(ba).
// ---------------------------------------------------------------------------
__global__ __launch_bounds__(256) void gather_k(
    const ushort* __restrict__ idxg,    // [32768][32]
    const uint*  __restrict__ Hu,       // [32769][64] bf16 pairs
    const float* __restrict__ ba,
    uint* __restrict__ aggu)            // [32768][64] bf16 pairs
{
    __shared__ ushort sidx[128];        // 4 nodes x 32
    const int l = threadIdx.x & 63;
    const int w = threadIdx.x >> 6;
    const int bid = blockIdx.x, xcd = bid & 7, grp = bid >> 3;
    const int batch = ((grp >> 9) << 3) + xcd;       // 0..15
    const int node0 = (batch << 11) + ((grp & 511) << 2);
    const int node = node0 + w;

    if (threadIdx.x < 64)
        ((uint*)sidx)[threadIdx.x] =
            ((const uint*)(idxg + (size_t)node0 * 32))[threadIdx.x];
    __syncthreads();

    uint h[32];
#pragma unroll
    for (int q = 0; q < 32; ++q)                     // all 32 in flight
        h[q] = Hu[(size_t)sidx[w * 32 + q] * 64 + l];

    float i0 = fmaxf(ba[2 * l], 0.f), i1 = fmaxf(ba[2 * l + 1], 0.f);
    float a0[8], a1[8];
#pragma unroll
    for (int q = 0; q < 8; ++q) { a0[q] = i0; a1[q] = i1; }
#pragma unroll
    for (int q = 0; q < 32; ++q) {
        a0[q & 7] = fmaxf(a0[q & 7], bflo(h[q]));
        a1[q & 7] = fmaxf(a1[q & 7], bfhi(h[q]));
    }
#pragma unroll
    for (int q = 0; q < 4; ++q) {
        a0[q] = fmaxf(a0[q], a0[q + 4]);
        a1[q] = fmaxf(a1[q], a1[q + 4]);
    }
    float r0f = fmaxf(fmaxf(a0[0], a0[1]), fmaxf(a0[2], a0[3]));
    float r1f = fmaxf(fmaxf(a1[0], a1[1]), fmaxf(a1[2], a1[3]));
    aggu[(size_t)node * 64 + l] = (uint)f2bf(r0f) | ((uint)f2bf(r1f) << 16);
}

// ---------------------------------------------------------------------------
// K3: out = relu([X|agg] @ Wc + bc), grid barrier, in-register frobenius
// normalize (div_no_nan), single store. 256 blocks @ 64KB LDS = 2/CU ->
// co-resident, spin barrier deadlock-free (R6-proven).
// ---------------------------------------------------------------------------
__global__ __launch_bounds__(256) void gemm_k3_k(
    const float* __restrict__ X, const ushort* __restrict__ agg,
    const ushort* __restrict__ Wct, const float* __restrict__ bc,
    float* __restrict__ out, float* __restrict__ partials,
    uint* __restrict__ ctr)
{
    __shared__ ushort Asm[128 * 128];
    __shared__ ushort Bsm[128 * 128];
    __shared__ float wred[4];
    __shared__ float ssc;
    const int tid = threadIdx.x, l = tid & 63, w = tid >> 6;
    const int wm = (w >> 1) * 64, wn = (w & 1) * 64;
    const int tile = blockIdx.x;
    const size_t row0 = (size_t)tile * 128;

    f32x4 acc[4][4] = {};
    for (int t = 0; t < 2; ++t) {
        __syncthreads();
        if (t == 0) {
#pragma unroll
            for (int j = 0; j < 8; ++j) {
                int gid = (j << 8) + tid;
                int r = gid >> 4, g = gid & 15;
                const float* s = X + (row0 + r) * 128 + g * 8;
                short8 pk;
#pragma unroll
                for (int e = 0; e < 8; ++e) pk[e] = (short)f2bf(s[e]);
                *(short8*)&Asm[r * 128 + ((g ^ (r & 7)) << 3)] = pk;
            }
        } else {
#pragma unroll
            for (int j = 0; j < 8; ++j) {
                int gid = (j << 8) + tid;
                int r = gid >> 4, g = gid & 15;
                short8 v = *(const short8*)(agg + (row0 + r) * 128 + g * 8);
                *(short8*)&Asm[r * 128 + ((g ^ (r & 7)) << 3)] = v;
            }
        }
#pragma unroll
        for (int j = 0; j < 8; ++j) {
            int gid = (j << 8) + tid;
            int r = gid >> 4, g = gid & 15;
            short8 v = *(const short8*)(Wct + (size_t)r * 256 + (t << 7) + g * 8);
            *(short8*)&Bsm[r * 128 + ((g ^ (r & 7)) << 3)] = v;
        }
        __syncthreads();
#pragma unroll
        for (int ks = 0; ks < 4; ++ks) {
            int gg = (ks << 2) + (l >> 4);
            short8 af[4], bfr[4];
#pragma unroll
            for (int m = 0; m < 4; ++m) {
                int r = wm + m * 16 + (l & 15);
                af[m] = *(const short8*)&Asm[r * 128 + ((gg ^ (r & 7)) << 3)];
            }
#pragma unroll
            for (int n = 0; n < 4; ++n) {
                int c = wn + n * 16 + (l & 15);
                bfr[n] = *(const short8*)&Bsm[c * 128 + ((gg ^ (c & 7)) << 3)];
            }
#pragma unroll
            for (int m = 0; m < 4; ++m)
#pragma unroll
                for (int n = 0; n < 4; ++n)
                    acc[m][n] = __builtin_amdgcn_mfma_f32_16x16x32_bf16(
                        af[m], bfr[n], acc[m][n], 0, 0, 0);
        }
    }

    float bcol[4];
#pragma unroll
    for (int n = 0; n < 4; ++n) bcol[n] = bc[wn + n * 16 + (l & 15)];
    float lsum = 0.f;
#pragma unroll
    for (int m = 0; m < 4; ++m)
#pragma unroll
        for (int n = 0; n < 4; ++n)
#pragma unroll
            for (int r = 0; r < 4; ++r) {
                float v = fmaxf(acc[m][n][r] + bcol[n], 0.f);
                acc[m][n][r] = v;                    // keep relu'd value
                lsum += v * v;
            }
#pragma unroll
    for (int off = 32; off > 0; off >>= 1) lsum += __shfl_down(lsum, off);
    if (l == 0) wred[w] = lsum;
    __syncthreads();
    if (tid == 0) {
        partials[tile] = wred[0] + wred[1] + wred[2] + wred[3];
        __threadfence();                             // release partials
        __hip_atomic_fetch_add(ctr, 1u, __ATOMIC_ACQ_REL,
                               __HIP_MEMORY_SCOPE_AGENT);
        while (__hip_atomic_load(ctr, __ATOMIC_ACQUIRE,
                                 __HIP_MEMORY_SCOPE_AGENT) < 256u)
            __builtin_amdgcn_s_sleep(8);
        float s = 0.f;
        const int bb = tile >> 4;                    // batch of this tile
#pragma unroll
        for (int i = 0; i < 16; ++i)
            s += __hip_atomic_load(&partials[bb * 16 + i], __ATOMIC_RELAXED,
                                   __HIP_MEMORY_SCOPE_AGENT);
        float norm = sqrtf(s);
        ssc = (norm > 0.f) ? (1.f / norm) : 0.f;     // div_no_nan
    }
    __syncthreads();
    const float sc = ssc;
#pragma unroll
    for (int m = 0; m < 4; ++m) {
        int rbase = wm + m * 16 + ((l >> 4) << 2);
#pragma unroll
        for (int n = 0; n < 4; ++n) {
            int col = wn + n * 16 + (l & 15);
#pragma unroll
            for (int r = 0; r < 4; ++r)
                out[(row0 + rbase + r) * 128 + col] = acc[m][n][r] * sc;
        }
    }
}

extern "C" void kernel_launch(void* const* d_in, const int* in_sizes, int n_in,
                              void* d_out, int out_size, void* d_ws, size_t ws_size,
                              hipStream_t stream) {
    const float* A  = (const float*)d_in[0];
    const float* X  = (const float*)d_in[1];
    const float* Wa = (const float*)d_in[2];
    const float* ba = (const float*)d_in[3];
    const float* Wc = (const float*)d_in[4];
    const float* bc = (const float*)d_in[5];
    const int*  nsp = (const int*)d_in[6];

    float* out = (float*)d_out;
    char* ws = (char*)d_ws;
    ushort* H        = (ushort*)ws;                              // 8.4 MB
    ushort* agg      = (ushort*)(ws + (9u << 20));               // 8 MB
    ushort* idxg     = (ushort*)(ws + (17u << 20));              // 2 MB
    ushort* Wct      = (ushort*)(ws + (19u << 20));              // 64 KB
    float*  partials = (float*) (ws + (19u << 20) + 65536);      // 1 KB
    uint*   ctr      = (uint*)  (ws + (19u << 20) + 66560);      // 4 B

    // K1: H = relu(X @ Wa + ba), inline Wa transpose; sentinel row 32768
    gemm_k1_k<<<256, 256, 0, stream>>>(X, Wa, ba, H);
    // scan: A-stream -> padded GLOBAL idx lists (+ Wct prep, + ctr zero)
    scan_k<<<8192 + 128, 256, 0, stream>>>(A, idxg, nsp, Wc, Wct, ctr);
    // gather: agg = max over idx'd H rows
    gather_k<<<8192, 256, 0, stream>>>(idxg, (const uint*)H, ba, (uint*)agg);
    // K3: GEMM + grid barrier + in-register normalize
    gemm_k3_k<<<256, 256, 0, stream>>>(X, agg, Wct, bc, out, partials, ctr);
}